// Round 3
// baseline (853.607 us; speedup 1.0000x reference)
//
#include <hip/hip_runtime.h>

#define MAPN 250000      // 500*500
#define NPIX 2097152     // 1024*2048

typedef unsigned short ushort_t;
typedef __attribute__((ext_vector_type(8))) short short8;
typedef __attribute__((ext_vector_type(4))) float f32x4;
typedef __attribute__((ext_vector_type(16))) float f32x16;

__device__ inline ushort_t f2bf(float f){
  unsigned u = __float_as_uint(f);
  u = (u + 0x7fffu + ((u >> 16) & 1u)) >> 16;
  return (ushort_t)u;
}
__device__ inline float bf2f(ushort_t h){ return __uint_as_float(((unsigned)h) << 16); }

// ---------------- input-format helpers ----------------
__device__ inline int read_mask(const void* p, int i, int t){
  if (t==0) return ((const int*)p)[i] != 0;
  if (t==1) return ((const unsigned char*)p)[i] != 0;
  if (t==3) return ((const long long*)p)[i] != 0;
  return ((const float*)p)[i] != 0.0f;
}
__device__ inline int read_idx(const void* p, int i, int t){
  if (t==1) return (int)((const long long*)p)[i];
  return ((const int*)p)[i];
}

__global__ void detect_kernel(const int* __restrict__ mask_w, const int* __restrict__ idx_w,
                              int* __restrict__ flags){
  int tid = threadIdx.x;
  int orv=0, modd=0, inz=0;
  for (int i=tid;i<4096;i+=256) orv |= mask_w[i];
  for (int i=tid;i<2048;i+=256) modd += (mask_w[2*i+1]!=0);
  for (int i=tid;i<2048;i+=256) inz  += (idx_w[2*i+1]!=0);
  __shared__ int sOr[256], sM[256], sI[256];
  sOr[tid]=orv; sM[tid]=modd; sI[tid]=inz; __syncthreads();
  for (int o=128;o;o>>=1){ if(tid<o){ sOr[tid]|=sOr[tid+o]; sM[tid]+=sM[tid+o]; sI[tid]+=sI[tid+o]; } __syncthreads(); }
  if (tid==0){
    int o = sOr[0];
    int mt;
    if ((o & ~1) == 0)               mt = (sM[0] > 0) ? 0 : 3;
    else if ((o & ~0x01010101) == 0) mt = 1;
    else                             mt = 2;
    flags[0] = mt;
    flags[1] = (sI[0] > 0) ? 0 : 1;
  }
}

// ---------------- feature transpose CHW -> HWC (fp32 -> bf16) ----------------
__global__ void feat_transpose(const float* __restrict__ f, ushort_t* __restrict__ out){
  __shared__ float tile[64][65];
  int tid = threadIdx.x;
  int y = blockIdx.y;
  int x0 = blockIdx.x * 64;
  #pragma unroll
  for (int pass=0; pass<16; pass++){
    int c = pass*4 + (tid>>6);
    int x = x0 + (tid & 63);
    tile[c][tid & 63] = f[(size_t)c*131072 + (size_t)y*512 + x];
  }
  __syncthreads();
  #pragma unroll
  for (int pass=0; pass<16; pass++){
    int xl = pass*4 + (tid>>6);
    int c  = tid & 63;
    out[((size_t)y*512 + x0 + xl)*64 + c] = f2bf(tile[c][xl]);
  }
}

// ---------------- mask compaction scan ----------------
__global__ void scan_count(const void* __restrict__ mask, const int* __restrict__ flags,
                           int* __restrict__ blkSums){
  int t = flags[0];
  int tid = threadIdx.x;
  int base = blockIdx.x*1024 + tid*4;
  int s = 0;
  #pragma unroll
  for (int j=0;j<4;j++) s += read_mask(mask, base+j, t);
  __shared__ int red[256];
  red[tid] = s; __syncthreads();
  for (int o=128;o;o>>=1){ if (tid<o) red[tid]+=red[tid+o]; __syncthreads(); }
  if (tid==0) blkSums[blockIdx.x] = red[0];
}

__global__ void scan_offsets(const int* __restrict__ blkSums, int* __restrict__ blkOffs){
  __shared__ int tsum[256];
  int tid = threadIdx.x;
  int loc[8]; int s=0;
  #pragma unroll
  for (int j=0;j<8;j++){ loc[j]=blkSums[tid*8+j]; s+=loc[j]; }
  tsum[tid]=s; __syncthreads();
  for (int o=1;o<256;o<<=1){
    int v = (tid>=o)? tsum[tid-o] : 0;
    __syncthreads();
    tsum[tid] += v;
    __syncthreads();
  }
  int run = tsum[tid]-s;
  #pragma unroll
  for (int j=0;j<8;j++){ blkOffs[tid*8+j]=run; run+=loc[j]; }
  if (tid==255) blkOffs[2048]=run;
}

__global__ void build_table(const void* __restrict__ mask, const int* __restrict__ flags,
                            const int* __restrict__ blkOffs, int* __restrict__ table){
  int t = flags[0];
  int tid = threadIdx.x;
  int base = blockIdx.x*1024 + tid*4;
  int mv[4]; int s=0;
  #pragma unroll
  for (int j=0;j<4;j++){ mv[j]=read_mask(mask, base+j, t); s+=mv[j]; }
  __shared__ int red[256];
  red[tid]=s; __syncthreads();
  for (int o=1;o<256;o<<=1){
    int v = (tid>=o)? red[tid-o] : 0;
    __syncthreads();
    red[tid]+=v;
    __syncthreads();
  }
  int excl = red[tid]-s + blkOffs[blockIdx.x];
  int total = blkOffs[2048];
  #pragma unroll
  for (int j=0;j<4;j++){
    int p = base+j;
    int pos;
    if (mv[j]){ pos = excl; excl++; }
    else      { pos = total + (p - excl); }
    table[pos] = p;
  }
}

// ---------------- max(idx) ----------------
__global__ void max_idx_kernel(const void* __restrict__ idxp, const int* __restrict__ flags,
                               int* __restrict__ mx){
  int t = flags[1];
  int m = 0;
  for (int i = blockIdx.x*blockDim.x + threadIdx.x; i < MAPN; i += gridDim.x*blockDim.x)
    m = max(m, read_idx(idxp, i, t));
  #pragma unroll
  for (int o=32;o;o>>=1) m = max(m, __shfl_down(m, o));
  if ((threadIdx.x & 63) == 0) atomicMax(mx, m);
}

// ---------------- gather + on-the-fly bilinear (bf16 in/out) ----------------
__global__ void gather_kernel(const void* __restrict__ idxp, const int* __restrict__ flags,
                              const int* __restrict__ mxp, const int* __restrict__ table,
                              const ushort_t* __restrict__ Fhwc, const float* __restrict__ rgb,
                              ushort_t* __restrict__ memory, float* __restrict__ out_obs,
                              float* __restrict__ out_rgb){
  int cell = blockIdx.x*4 + (threadIdx.x>>6);
  int lane = threadIdx.x & 63;
  int t = flags[1];
  int mx = *mxp;
  int idx = read_idx(idxp, cell, t);
  bool m = idx < mx;
  float v = 0.0f, r = 0.0f;
  if (m){
    int p = table[idx];
    int py = p >> 11, px = p & 2047;
    float fy = py * (255.0f/1023.0f);
    int y0 = (int)fy; float wy = fy - (float)y0; int y1 = min(y0+1, 255);
    float fx = px * (511.0f/2047.0f);
    int x0 = (int)fx; float wx = fx - (float)x0; int x1 = min(x0+1, 511);
    const ushort_t* f00 = Fhwc + ((size_t)y0*512 + x0)*64;
    const ushort_t* f01 = Fhwc + ((size_t)y0*512 + x1)*64;
    const ushort_t* f10 = Fhwc + ((size_t)y1*512 + x0)*64;
    const ushort_t* f11 = Fhwc + ((size_t)y1*512 + x1)*64;
    float w00=(1.0f-wy)*(1.0f-wx), w01=(1.0f-wy)*wx, w10=wy*(1.0f-wx), w11=wy*wx;
    v = w00*bf2f(f00[lane]) + w01*bf2f(f01[lane]) + w10*bf2f(f10[lane]) + w11*bf2f(f11[lane]);
    if (lane < 3) r = rgb[(size_t)p*3 + lane];
  }
  memory[(size_t)cell*64 + lane] = f2bf(v);
  if (lane == 0) out_obs[cell] = m ? 1.0f : 0.0f;
  if (lane < 3)  out_rgb[(size_t)cell*3 + lane] = r;
}

// ---------------- weight prep: OIHW fp32 -> [O][KK][CIPAD] bf16 ----------------
__global__ void wprep(const float* __restrict__ w, ushort_t* __restrict__ out,
                      int O, int I, int KK, int CIPAD){
  int n = O*KK*CIPAD;
  for (int e = blockIdx.x*blockDim.x + threadIdx.x; e < n; e += gridDim.x*blockDim.x){
    int o = e/(KK*CIPAD); int r = e - o*KK*CIPAD; int k = r/CIPAD; int ci = r - k*CIPAD;
    float v = (ci < I) ? w[((size_t)o*I + ci)*KK + k] : 0.0f;
    out[e] = f2bf(v);
  }
}

// ---------------- L1: 7x7 64->128 row-tiled halo MFMA conv ----------------
// in:  bf16 [MAPN][64]; wt: bf16 [128][49][64]; out: bf16 [MAPN][128]
// partials: fp32 [1000][256]  (sum[128], sumsq[128])
#define MFMA32(a,b,c) __builtin_amdgcn_mfma_f32_32x32x16_bf16(a,b,c,0,0,0)

__global__ __launch_bounds__(256, 2) void conv7_row(const ushort_t* __restrict__ in,
                                                    const ushort_t* __restrict__ wt,
                                                    ushort_t* __restrict__ out,
                                                    float* __restrict__ partials){
  constexpr int EH = 272;                 // staged halo entries (need 262)
  __shared__ char sA[EH*128];             // [e][64ci] bf16, XOR-swizzled
  __shared__ char sB[2][128*128];         // [co][64ci] bf16, XOR-swizzled
  __shared__ float sStat[4][2][32][2];

  int tid = threadIdx.x;
  int lane = tid & 63;
  int wv = tid >> 6;
  int wm = wv >> 1, wn = wv & 1;          // 2x2 wave grid: M-half, CO-half
  int y  = blockIdx.x;                    // 0..499
  int xh = blockIdx.y;                    // 0..1
  int x0 = xh * 256;

  f32x16 acc[4][2];
  #pragma unroll
  for (int mi=0;mi<4;mi++)
    #pragma unroll
    for (int ni=0;ni<2;ni++) acc[mi][ni] = (f32x16)0.0f;

  // ---- stage B for tap 0 into buf 0 ----
  {
    #pragma unroll
    for (int i=0;i<4;i++){
      int f = i*256 + tid;
      int co = f>>3, cg = f&7;
      uint4 v = *(const uint4*)(wt + ((size_t)co*49 + 0)*64 + cg*8);
      unsigned wa = ((unsigned)(co*128 + cg*16)) ^ ((unsigned)(co&7)<<4);
      *(uint4*)(sB[0] + wa) = v;
    }
  }
  int cur = 0;

  for (int kh=0; kh<7; kh++){
    // ---- stage A for this kh (halo +-3) ----
    {
      int yy = y + kh - 3;
      bool rowok = (unsigned)yy < 500u;
      for (int i=0;i<9;i++){
        int f = i*256 + tid;
        if (f < EH*8){
          int e = f>>3, cg = f&7;
          int xs = x0 + e - 3;
          uint4 v = make_uint4(0u,0u,0u,0u);
          if (rowok && (unsigned)xs < 500u)
            v = *(const uint4*)(in + ((size_t)yy*500 + xs)*64 + cg*8);
          unsigned wa = ((unsigned)(e*128 + cg*16)) ^ ((unsigned)(e&7)<<4);
          *(uint4*)(sA + wa) = v;
        }
      }
    }
    __syncthreads();   // A ready (and B for first tap of this kh)

    for (int kw=0; kw<7; kw++){
      int tap = kh*7 + kw;
      // prefetch next tap's B into the other buffer
      if (tap < 48){
        #pragma unroll
        for (int i=0;i<4;i++){
          int f = i*256 + tid;
          int co = f>>3, cg = f&7;
          uint4 v = *(const uint4*)(wt + ((size_t)co*49 + (tap+1))*64 + cg*8);
          unsigned wa = ((unsigned)(co*128 + cg*16)) ^ ((unsigned)(co&7)<<4);
          *(uint4*)(sB[cur^1] + wa) = v;
        }
      }
      // compute: 4 kc x (4 mi x 2 ni)
      #pragma unroll
      for (int kc=0; kc<4; kc++){
        short8 bfr[2];
        #pragma unroll
        for (int ni=0;ni<2;ni++){
          int co = wn*64 + ni*32 + (lane&31);
          unsigned rb = ((unsigned)(co*128 + kc*32 + (lane>>5)*16)) ^ ((unsigned)(co&7)<<4);
          bfr[ni] = *(const short8*)(sB[cur] + rb);
        }
        #pragma unroll
        for (int mi=0;mi<4;mi++){
          int e = wm*128 + mi*32 + (lane&31) + kw;
          unsigned ra = ((unsigned)(e*128 + kc*32 + (lane>>5)*16)) ^ ((unsigned)(e&7)<<4);
          short8 afr = *(const short8*)(sA + ra);
          acc[mi][0] = MFMA32(afr, bfr[0], acc[mi][0]);
          acc[mi][1] = MFMA32(afr, bfr[1], acc[mi][1]);
        }
      }
      __syncthreads();   // compute done; buffers may be overwritten next iter
      cur ^= 1;
    }
  }

  // ---- epilogue: store + BN partials ----
  // C/D layout (32x32): col = lane&31, row = (r&3) + 8*(r>>2) + 4*(lane>>5)
  #pragma unroll
  for (int ni=0;ni<2;ni++){
    float s = 0.f, q = 0.f;
    #pragma unroll
    for (int mi=0;mi<4;mi++){
      #pragma unroll
      for (int r=0;r<16;r++){
        int row = (r&3) + 8*(r>>2) + 4*(lane>>5);
        int x = x0 + wm*128 + mi*32 + row;
        float v = acc[mi][ni][r];
        if (x < 500){
          s += v; q += v*v;
          out[((size_t)y*500 + x)*128 + wn*64 + ni*32 + (lane&31)] = f2bf(v);
        }
      }
    }
    s += __shfl_xor(s, 32); q += __shfl_xor(q, 32);
    if (lane < 32){ sStat[wv][ni][lane][0] = s; sStat[wv][ni][lane][1] = q; }
  }
  __syncthreads();
  if (tid < 128){
    int c = tid;
    int wn_ = c>>6, ni_ = (c>>5)&1, col = c&31;
    float s = sStat[0*2+wn_][ni_][col][0] + sStat[1*2+wn_][ni_][col][0];
    float q = sStat[0*2+wn_][ni_][col][1] + sStat[1*2+wn_][ni_][col][1];
    int blk = blockIdx.y*500 + blockIdx.x;
    partials[(size_t)blk*256 + c]       = s;
    partials[(size_t)blk*256 + 128 + c] = q;
  }
}

// ---------------- MFMA implicit-GEMM conv with fused input-BN+ReLU ----------------
// HASBN: input is raw previous-conv output; apply y = relu(x*sc + sh) per input
// channel (ci < CIREAL) during staging; channels >= CIREAL are zeroed.
template<int CI, int CO, int COPAD, int KS, int PAD, bool HASBN, int CIREAL>
__global__ __launch_bounds__(256) void conv_mfma(const ushort_t* __restrict__ in,
                                                 const ushort_t* __restrict__ wt,
                                                 const float* __restrict__ scsh,
                                                 ushort_t* __restrict__ out,
                                                 float* __restrict__ partials){
  constexpr int NF  = CO/16;
  constexpr int CIG = CI/8;
  constexpr int AIT = (128*CIG)/256;
  constexpr int BCH = CO*CIG;
  constexpr int BIT = (BCH+255)/256;
  __shared__ char sA[128*CI*2];
  __shared__ char sB[CO*CI*2];
  __shared__ float sStat[4][NF][16][2];
  __shared__ float sSc[CI], sSh[CI];

  int tid = threadIdx.x;
  int wv = tid >> 6, lane = tid & 63;
  int p0 = blockIdx.x * 128;

  if (HASBN){
    for (int i=tid;i<CIREAL;i+=256){ sSc[i]=scsh[i]; sSh[i]=scsh[CIREAL+i]; }
    __syncthreads();
  }

  int ay[AIT], ax[AIT];
  #pragma unroll
  for (int i=0;i<AIT;i++){
    int c = i*256 + tid;
    int pix = c / CIG;
    int p = p0 + pix;
    int yq = (int)((unsigned)p / 500u);
    ay[i]=yq; ax[i]=p - yq*500;
  }

  f32x4 acc[2][NF];
  #pragma unroll
  for (int mi=0;mi<2;mi++)
    #pragma unroll
    for (int ni=0;ni<NF;ni++) acc[mi][ni] = (f32x4)0.0f;

  for (int t=0; t<KS*KS; t++){
    int kh = t/KS, kw = t%KS;
    int dy = kh-PAD, dx = kw-PAD;
    int off = dy*500 + dx;
    #pragma unroll
    for (int i=0;i<AIT;i++){
      int c = i*256 + tid;
      int pix = c / CIG, cig8 = (c % CIG)*8;
      int p = p0 + pix;
      int ys = ay[i]+dy, xs = ax[i]+dx;
      bool valid = (p < MAPN) && ((unsigned)ys < 500u) && ((unsigned)xs < 500u)
                   && (!HASBN || cig8 < CIREAL);
      uint4 v = make_uint4(0u,0u,0u,0u);
      if (valid){
        v = *(const uint4*)(in + (size_t)(p+off)*CI + cig8);
        if (HASBN){
          ushort_t* hv = (ushort_t*)&v;
          #pragma unroll
          for (int j=0;j<8;j++){
            float f = bf2f(hv[j]);
            f = fmaxf(fmaf(f, sSc[cig8+j], sSh[cig8+j]), 0.0f);
            hv[j] = f2bf(f);
          }
        }
      }
      unsigned wa = ((unsigned)(pix*CI + cig8)*2u) ^ ((unsigned)(pix&7)<<4);
      *(uint4*)(sA + wa) = v;
    }
    #pragma unroll
    for (int i=0;i<BIT;i++){
      int c = i*256 + tid;
      if ((BCH % 256 == 0) || c < BCH){
        int co = c / CIG, cig8 = (c % CIG)*8;
        uint4 v = *(const uint4*)(wt + ((size_t)co*(KS*KS) + t)*CI + cig8);
        unsigned wb = ((unsigned)(co*CI + cig8)*2u) ^ ((unsigned)(co&7)<<4);
        *(uint4*)(sB + wb) = v;
      }
    }
    __syncthreads();
    #pragma unroll
    for (int kc=0; kc<CI/32; kc++){
      int ciL = kc*32 + (lane>>4)*8;
      short8 af[2];
      #pragma unroll
      for (int mi=0;mi<2;mi++){
        int pix = wv*32 + mi*16 + (lane&15);
        unsigned ra = ((unsigned)(pix*CI + ciL)*2u) ^ ((unsigned)(pix&7)<<4);
        af[mi] = *(const short8*)(sA + ra);
      }
      #pragma unroll
      for (int ni=0;ni<NF;ni++){
        int co = ni*16 + (lane&15);
        unsigned rb = ((unsigned)(co*CI + ciL)*2u) ^ ((unsigned)(co&7)<<4);
        short8 bfr = *(const short8*)(sB + rb);
        acc[0][ni] = __builtin_amdgcn_mfma_f32_16x16x32_bf16(af[0], bfr, acc[0][ni], 0,0,0);
        acc[1][ni] = __builtin_amdgcn_mfma_f32_16x16x32_bf16(af[1], bfr, acc[1][ni], 0,0,0);
      }
    }
    __syncthreads();
  }

  #pragma unroll
  for (int ni=0;ni<NF;ni++){
    float ps=0.f, pq=0.f;
    #pragma unroll
    for (int mi=0;mi<2;mi++){
      int prow = p0 + wv*32 + mi*16 + (lane>>4)*4;
      #pragma unroll
      for (int j=0;j<4;j++){
        float v = acc[mi][ni][j];
        ps += v; pq += v*v;
        int p = prow + j;
        if (p < MAPN) out[(size_t)p*COPAD + ni*16 + (lane&15)] = f2bf(v);
      }
    }
    ps += __shfl_xor(ps, 16); pq += __shfl_xor(pq, 16);
    ps += __shfl_xor(ps, 32); pq += __shfl_xor(pq, 32);
    if (lane < 16){ sStat[wv][ni][lane][0]=ps; sStat[wv][ni][lane][1]=pq; }
  }
  __syncthreads();
  if (tid < CO){
    float s = 0.f, q = 0.f;
    #pragma unroll
    for (int w=0;w<4;w++){ s += sStat[w][tid>>4][tid&15][0]; q += sStat[w][tid>>4][tid&15][1]; }
    partials[(size_t)blockIdx.x*(2*CO) + tid]      = s;
    partials[(size_t)blockIdx.x*(2*CO) + CO + tid] = q;
  }
}

// ---------------- BN: reduce per-block partials -> scale/shift ----------------
template<int CO>
__global__ void bn_reduce(const float* __restrict__ partials, int nblk,
                          const float* __restrict__ g, const float* __restrict__ b,
                          float* __restrict__ scsh){
  int c = blockIdx.x;
  float s=0.f, q=0.f;
  for (int i=threadIdx.x; i<nblk; i+=256){
    s += partials[(size_t)i*(2*CO) + c];
    q += partials[(size_t)i*(2*CO) + CO + c];
  }
  __shared__ float rs[256], rq[256];
  rs[threadIdx.x]=s; rq[threadIdx.x]=q; __syncthreads();
  for (int o=128;o;o>>=1){
    if (threadIdx.x<o){ rs[threadIdx.x]+=rs[threadIdx.x+o]; rq[threadIdx.x]+=rq[threadIdx.x+o]; }
    __syncthreads();
  }
  if (threadIdx.x==0){
    float mean = rs[0]*(1.0f/(float)MAPN);
    float var  = rq[0]*(1.0f/(float)MAPN) - mean*mean;
    float inv  = rsqrtf(var + 1e-5f);
    float sc   = g[c]*inv;
    scsh[c]    = sc;
    scsh[CO+c] = b[c] - mean*sc;
  }
}

// ---------------- final 1x1 conv + bias (fused input BN+ReLU), NCHW out ----------------
__global__ void conv5_kernel(const ushort_t* __restrict__ in, const float* __restrict__ w,
                             const float* __restrict__ bias, const float* __restrict__ scsh,
                             float* __restrict__ out){
  __shared__ float sw[21*48];
  __shared__ float sb[21];
  __shared__ float sc[48], sh[48];
  for (int i=threadIdx.x;i<1008;i+=256) sw[i]=w[i];
  if (threadIdx.x<21) sb[threadIdx.x]=bias[threadIdx.x];
  if (threadIdx.x<48){ sc[threadIdx.x]=scsh[threadIdx.x]; sh[threadIdx.x]=scsh[48+threadIdx.x]; }
  __syncthreads();
  int pix = blockIdx.x*256 + threadIdx.x;
  if (pix >= MAPN) return;
  float acc[21];
  #pragma unroll
  for (int i=0;i<21;i++) acc[i]=0.0f;
  const ushort_t* ip = in + (size_t)pix*64;
  #pragma unroll
  for (int cg=0; cg<6; cg++){
    uint4 v = *(const uint4*)(ip + cg*8);
    ushort_t* hv = (ushort_t*)&v;
    #pragma unroll
    for (int j=0;j<8;j++){
      int ci = cg*8+j;
      float s = fmaxf(fmaf(bf2f(hv[j]), sc[ci], sh[ci]), 0.0f);
      #pragma unroll
      for (int co=0;co<21;co++) acc[co]=fmaf(s, sw[co*48+ci], acc[co]);
    }
  }
  #pragma unroll
  for (int co=0;co<21;co++) out[(size_t)co*MAPN + pix] = acc[co] + sb[co];
}

// ---------------- host launch ----------------
static inline size_t al256(size_t x){ return (x + 255) & ~(size_t)255; }

extern "C" void kernel_launch(void* const* d_in, const int* in_sizes, int n_in,
                              void* d_out, int out_size, void* d_ws, size_t ws_size,
                              hipStream_t stream){
  const float* features = (const float*)d_in[0];
  const void*  proj     = d_in[1];
  const void*  mask     = d_in[2];
  const float* rgb      = (const float*)d_in[3];
  const float* w1 = (const float*)d_in[4];
  const float* g1 = (const float*)d_in[5];
  const float* b1 = (const float*)d_in[6];
  const float* w2 = (const float*)d_in[7];
  const float* g2 = (const float*)d_in[8];
  const float* b2 = (const float*)d_in[9];
  const float* w3 = (const float*)d_in[10];
  const float* g3 = (const float*)d_in[11];
  const float* b3 = (const float*)d_in[12];
  const float* w4 = (const float*)d_in[13];
  const float* g4 = (const float*)d_in[14];
  const float* b4 = (const float*)d_in[15];
  const float* w5 = (const float*)d_in[16];
  const float* b5 = (const float*)d_in[17];

  const int NBLK = (MAPN + 127)/128;   // 1954 (for conv_mfma layers)

  char* ws = (char*)d_ws;
  size_t off = 0;
  ushort_t* mem_bf = (ushort_t*)(ws + off); off += al256((size_t)MAPN*64*2);
  ushort_t* actA   = (ushort_t*)(ws + off); off += al256((size_t)MAPN*128*2);
  ushort_t* actB   = (ushort_t*)(ws + off); off += al256((size_t)MAPN*64*2);
  ushort_t* Fhwc   = (ushort_t*)(ws + off); off += al256((size_t)131072*64*2);
  int*      table  = (int*)(ws + off);      off += al256((size_t)NPIX*4);
  ushort_t* wh1    = (ushort_t*)(ws + off); off += al256((size_t)128*49*64*2);
  ushort_t* wh2    = (ushort_t*)(ws + off); off += al256((size_t)64*9*128*2);
  ushort_t* wh3    = (ushort_t*)(ws + off); off += al256((size_t)48*9*64*2);
  ushort_t* wh4    = (ushort_t*)(ws + off); off += al256((size_t)48*9*64*2);
  float*    partials = (float*)(ws + off);  off += al256((size_t)NBLK*2*128*4);
  int* blkSums = (int*)(ws + off); off += al256(2048*4);
  int* blkOffs = (int*)(ws + off); off += al256(2049*4);
  int* maxidx  = (int*)(ws + off); off += 256;
  int* flags   = (int*)(ws + off); off += 256;
  float* scsh1 = (float*)(ws + off); off += al256(256*4);
  float* scsh2 = (float*)(ws + off); off += al256(256*4);
  float* scsh3 = (float*)(ws + off); off += al256(256*4);
  float* scsh4 = (float*)(ws + off); off += al256(256*4);

  float* out_sem = (float*)d_out;
  float* out_obs = out_sem + (size_t)21*MAPN;
  float* out_rgb = out_obs + MAPN;

  detect_kernel<<<1,256,0,stream>>>((const int*)mask, (const int*)proj, flags);
  feat_transpose<<<dim3(8,256),256,0,stream>>>(features, Fhwc);

  scan_count<<<2048,256,0,stream>>>(mask, flags, blkSums);
  scan_offsets<<<1,256,0,stream>>>(blkSums, blkOffs);
  build_table<<<2048,256,0,stream>>>(mask, flags, blkOffs, table);

  hipMemsetAsync(maxidx, 0, 4, stream);
  max_idx_kernel<<<256,256,0,stream>>>(proj, flags, maxidx);

  wprep<<<256,256,0,stream>>>(w1, wh1, 128, 64, 49, 64);
  wprep<<<64,256,0,stream>>>(w2, wh2, 64, 128, 9, 128);
  wprep<<<32,256,0,stream>>>(w3, wh3, 48, 64, 9, 64);
  wprep<<<32,256,0,stream>>>(w4, wh4, 48, 48, 9, 64);

  gather_kernel<<<62500,256,0,stream>>>(proj, flags, maxidx, table, Fhwc, rgb,
                                        mem_bf, out_obs, out_rgb);

  // L1: 7x7 64->128 (row-tiled halo kernel), BN stats fused
  conv7_row<<<dim3(500,2),256,0,stream>>>(mem_bf, wh1, actA, partials);
  bn_reduce<128><<<128,256,0,stream>>>(partials, 1000, g1, b1, scsh1);

  // L2: 3x3 128->64, input-BN(L1) fused into staging
  conv_mfma<128,64,64,3,1,true,128><<<NBLK,256,0,stream>>>(actA, wh2, scsh1, actB, partials);
  bn_reduce<64><<<64,256,0,stream>>>(partials, NBLK, g2, b2, scsh2);

  // L3: 3x3 64->48 (pad 64), input-BN(L2) fused
  conv_mfma<64,48,64,3,1,true,64><<<NBLK,256,0,stream>>>(actB, wh3, scsh2, actA, partials);
  bn_reduce<48><<<48,256,0,stream>>>(partials, NBLK, g3, b3, scsh3);

  // L4: 3x3 48(pad64)->48 (pad 64), input-BN(L3) fused (ci>=48 zeroed)
  conv_mfma<64,48,64,3,1,true,48><<<NBLK,256,0,stream>>>(actA, wh4, scsh3, actB, partials);
  bn_reduce<48><<<48,256,0,stream>>>(partials, NBLK, g4, b4, scsh4);

  // L5: 1x1 48->21 + bias, input-BN(L4) fused, NCHW out
  conv5_kernel<<<(MAPN+255)/256,256,0,stream>>>(actB, w5, b5, scsh4, out_sem);
}

// Round 4
// 712.114 us; speedup vs baseline: 1.1987x; 1.1987x over previous
//
#include <hip/hip_runtime.h>

#define MAPN 250000      // 500*500
#define NPIX 2097152     // 1024*2048

typedef unsigned short ushort_t;
typedef __attribute__((ext_vector_type(8))) short short8;
typedef __attribute__((ext_vector_type(4))) float f32x4;

__device__ inline ushort_t f2bf(float f){
  unsigned u = __float_as_uint(f);
  u = (u + 0x7fffu + ((u >> 16) & 1u)) >> 16;
  return (ushort_t)u;
}
__device__ inline float bf2f(ushort_t h){ return __uint_as_float(((unsigned)h) << 16); }

__device__ __forceinline__ void glds16(const void* g, void* l){
  __builtin_amdgcn_global_load_lds((const __attribute__((address_space(1))) unsigned int*)g,
                                   (__attribute__((address_space(3))) unsigned int*)l, 16, 0, 0);
}

// ---------------- input-format helpers ----------------
__device__ inline int read_mask(const void* p, int i, int t){
  if (t==0) return ((const int*)p)[i] != 0;
  if (t==1) return ((const unsigned char*)p)[i] != 0;
  if (t==3) return ((const long long*)p)[i] != 0;
  return ((const float*)p)[i] != 0.0f;
}
__device__ inline int read_idx(const void* p, int i, int t){
  if (t==1) return (int)((const long long*)p)[i];
  return ((const int*)p)[i];
}

__global__ void detect_kernel(const int* __restrict__ mask_w, const int* __restrict__ idx_w,
                              int* __restrict__ flags){
  int tid = threadIdx.x;
  int orv=0, modd=0, inz=0;
  for (int i=tid;i<4096;i+=256) orv |= mask_w[i];
  for (int i=tid;i<2048;i+=256) modd += (mask_w[2*i+1]!=0);
  for (int i=tid;i<2048;i+=256) inz  += (idx_w[2*i+1]!=0);
  __shared__ int sOr[256], sM[256], sI[256];
  sOr[tid]=orv; sM[tid]=modd; sI[tid]=inz; __syncthreads();
  for (int o=128;o;o>>=1){ if(tid<o){ sOr[tid]|=sOr[tid+o]; sM[tid]+=sM[tid+o]; sI[tid]+=sI[tid+o]; } __syncthreads(); }
  if (tid==0){
    int o = sOr[0];
    int mt;
    if ((o & ~1) == 0)               mt = (sM[0] > 0) ? 0 : 3;
    else if ((o & ~0x01010101) == 0) mt = 1;
    else                             mt = 2;
    flags[0] = mt;
    flags[1] = (sI[0] > 0) ? 0 : 1;
  }
}

// ---------------- feature transpose CHW -> HWC (fp32 -> bf16) ----------------
__global__ void feat_transpose(const float* __restrict__ f, ushort_t* __restrict__ out){
  __shared__ float tile[64][65];
  int tid = threadIdx.x;
  int y = blockIdx.y;
  int x0 = blockIdx.x * 64;
  #pragma unroll
  for (int pass=0; pass<16; pass++){
    int c = pass*4 + (tid>>6);
    int x = x0 + (tid & 63);
    tile[c][tid & 63] = f[(size_t)c*131072 + (size_t)y*512 + x];
  }
  __syncthreads();
  #pragma unroll
  for (int pass=0; pass<16; pass++){
    int xl = pass*4 + (tid>>6);
    int c  = tid & 63;
    out[((size_t)y*512 + x0 + xl)*64 + c] = f2bf(tile[c][xl]);
  }
}

// ---------------- mask compaction scan ----------------
__global__ void scan_count(const void* __restrict__ mask, const int* __restrict__ flags,
                           int* __restrict__ blkSums){
  int t = flags[0];
  int tid = threadIdx.x;
  int base = blockIdx.x*1024 + tid*4;
  int s = 0;
  #pragma unroll
  for (int j=0;j<4;j++) s += read_mask(mask, base+j, t);
  __shared__ int red[256];
  red[tid] = s; __syncthreads();
  for (int o=128;o;o>>=1){ if (tid<o) red[tid]+=red[tid+o]; __syncthreads(); }
  if (tid==0) blkSums[blockIdx.x] = red[0];
}

__global__ void scan_offsets(const int* __restrict__ blkSums, int* __restrict__ blkOffs){
  __shared__ int tsum[256];
  int tid = threadIdx.x;
  int loc[8]; int s=0;
  #pragma unroll
  for (int j=0;j<8;j++){ loc[j]=blkSums[tid*8+j]; s+=loc[j]; }
  tsum[tid]=s; __syncthreads();
  for (int o=1;o<256;o<<=1){
    int v = (tid>=o)? tsum[tid-o] : 0;
    __syncthreads();
    tsum[tid] += v;
    __syncthreads();
  }
  int run = tsum[tid]-s;
  #pragma unroll
  for (int j=0;j<8;j++){ blkOffs[tid*8+j]=run; run+=loc[j]; }
  if (tid==255) blkOffs[2048]=run;
}

__global__ void build_table(const void* __restrict__ mask, const int* __restrict__ flags,
                            const int* __restrict__ blkOffs, int* __restrict__ table){
  int t = flags[0];
  int tid = threadIdx.x;
  int base = blockIdx.x*1024 + tid*4;
  int mv[4]; int s=0;
  #pragma unroll
  for (int j=0;j<4;j++){ mv[j]=read_mask(mask, base+j, t); s+=mv[j]; }
  __shared__ int red[256];
  red[tid]=s; __syncthreads();
  for (int o=1;o<256;o<<=1){
    int v = (tid>=o)? red[tid-o] : 0;
    __syncthreads();
    red[tid]+=v;
    __syncthreads();
  }
  int excl = red[tid]-s + blkOffs[blockIdx.x];
  int total = blkOffs[2048];
  #pragma unroll
  for (int j=0;j<4;j++){
    int p = base+j;
    int pos;
    if (mv[j]){ pos = excl; excl++; }
    else      { pos = total + (p - excl); }
    table[pos] = p;
  }
}

// ---------------- max(idx) ----------------
__global__ void max_idx_kernel(const void* __restrict__ idxp, const int* __restrict__ flags,
                               int* __restrict__ mx){
  int t = flags[1];
  int m = 0;
  for (int i = blockIdx.x*blockDim.x + threadIdx.x; i < MAPN; i += gridDim.x*blockDim.x)
    m = max(m, read_idx(idxp, i, t));
  #pragma unroll
  for (int o=32;o;o>>=1) m = max(m, __shfl_down(m, o));
  if ((threadIdx.x & 63) == 0) atomicMax(mx, m);
}

// ---------------- gather + on-the-fly bilinear (bf16 in/out) ----------------
__global__ void gather_kernel(const void* __restrict__ idxp, const int* __restrict__ flags,
                              const int* __restrict__ mxp, const int* __restrict__ table,
                              const ushort_t* __restrict__ Fhwc, const float* __restrict__ rgb,
                              ushort_t* __restrict__ memory, float* __restrict__ out_obs,
                              float* __restrict__ out_rgb){
  int cell = blockIdx.x*4 + (threadIdx.x>>6);
  int lane = threadIdx.x & 63;
  int t = flags[1];
  int mx = *mxp;
  int idx = read_idx(idxp, cell, t);
  bool m = idx < mx;
  float v = 0.0f, r = 0.0f;
  if (m){
    int p = table[idx];
    int py = p >> 11, px = p & 2047;
    float fy = py * (255.0f/1023.0f);
    int y0 = (int)fy; float wy = fy - (float)y0; int y1 = min(y0+1, 255);
    float fx = px * (511.0f/2047.0f);
    int x0 = (int)fx; float wx = fx - (float)x0; int x1 = min(x0+1, 511);
    const ushort_t* f00 = Fhwc + ((size_t)y0*512 + x0)*64;
    const ushort_t* f01 = Fhwc + ((size_t)y0*512 + x1)*64;
    const ushort_t* f10 = Fhwc + ((size_t)y1*512 + x0)*64;
    const ushort_t* f11 = Fhwc + ((size_t)y1*512 + x1)*64;
    float w00=(1.0f-wy)*(1.0f-wx), w01=(1.0f-wy)*wx, w10=wy*(1.0f-wx), w11=wy*wx;
    v = w00*bf2f(f00[lane]) + w01*bf2f(f01[lane]) + w10*bf2f(f10[lane]) + w11*bf2f(f11[lane]);
    if (lane < 3) r = rgb[(size_t)p*3 + lane];
  }
  memory[(size_t)cell*64 + lane] = f2bf(v);
  if (lane == 0) out_obs[cell] = m ? 1.0f : 0.0f;
  if (lane < 3)  out_rgb[(size_t)cell*3 + lane] = r;
}

// ---------------- weight prep: OIHW fp32 -> fragment-major bf16 ----------------
// layout: elem addr = (((t*KC + kc)*NF + ni)*64 + l)*8 + j
//   co = ni*16 + (l&15), ci = kc*32 + (l>>4)*8 + j, tap = t
__global__ void wprep_frag(const float* __restrict__ w, ushort_t* __restrict__ out,
                           int O, int I, int KK, int KC, int NF){
  int total = KK*KC*NF*512;
  for (int e = blockIdx.x*blockDim.x + threadIdx.x; e < total; e += gridDim.x*blockDim.x){
    int j = e & 7;
    int l = (e>>3) & 63;
    int fi = e >> 9;
    int ni = fi % NF; int rem = fi / NF;
    int kc = rem % KC; int t = rem / KC;
    int co = ni*16 + (l&15);
    int ci = kc*32 + (l>>4)*8 + j;
    float v = (ci < I) ? w[((size_t)co*I + ci)*KK + t] : 0.0f;
    out[e] = f2bf(v);
  }
}

// ---------------- MFMA implicit-GEMM conv: per-kh halo staging + glds B dbuf ----------------
// in:  bf16 NHWC [MAPN][CI]; wt: fragment-major (wprep_frag); out: bf16 NHWC [MAPN][COPAD]
// partials: fp32 [nblk][2*CO]
template<int CI, int CO, int COPAD, int KS, int PAD, bool HASBN, int CIREAL, int WM, int WN>
__global__ __launch_bounds__(256) void conv_khs(const ushort_t* __restrict__ in,
                                                const ushort_t* __restrict__ wt,
                                                const float* __restrict__ scsh,
                                                ushort_t* __restrict__ out,
                                                float* __restrict__ partials){
  constexpr int MI  = 128/(16*WM);     // 16-row A fragments per wave
  constexpr int NFW = CO/(16*WN);      // 16-col B fragments per wave
  constexpr int NF  = CO/16;
  constexpr int KC  = CI/32;
  constexpr int E   = 128 + 2*PAD;     // halo entries per kh
  constexpr int CIG = CI/8;
  constexpr int TB  = CO*CI*2;         // bytes per B tap
  constexpr int NSL = TB/1024;         // 1KB slices per tap
  constexpr int NT  = KS*KS;
  constexpr int TOT = E*CIG;
  constexpr int PASSES = (TOT+255)/256;
  constexpr int SCN = HASBN ? CI : 1;

  __shared__ char sA[E*CI*2];
  __shared__ char sB[2][TB];
  __shared__ float sStat[4][NFW][16][2];
  __shared__ float sSc[SCN], sSh[SCN];

  int tid = threadIdx.x;
  int lane = tid & 63;
  int wv = tid >> 6;
  int wm = wv / WN, wn = wv % WN;
  int p0 = blockIdx.x * 128;

  if (HASBN){
    for (int i=tid;i<CIREAL;i+=256){ sSc[i]=scsh[i]; sSh[i]=scsh[CIREAL+i]; }
    __syncthreads();
  }

  // per-mi output-pixel coords for x-validity masking
  int xc[MI]; bool pv[MI];
  #pragma unroll
  for (int mi=0;mi<MI;mi++){
    int p = p0 + wm*(MI*16) + mi*16 + (lane&15);
    pv[mi] = p < MAPN;
    xc[mi] = p % 500;
  }

  f32x4 acc[MI][NFW];
  #pragma unroll
  for (int mi=0;mi<MI;mi++)
    #pragma unroll
    for (int ni=0;ni<NFW;ni++) acc[mi][ni] = (f32x4)0.0f;

  // prefetch B tap 0 into buf 0 (pure DMA, drains at first barrier)
  for (int s=wv; s<NSL; s+=4)
    glds16((const char*)wt + (size_t)s*1024 + lane*16, &sB[0][s*1024]);

  const short8 zfrag = (short8)(short)0;
  int cur = 0;

  for (int kh=0; kh<KS; kh++){
    // ---- stage A halo for this kh (flat-bounds guard; x-wrap handled at read) ----
    {
      int q0 = p0 + (kh-PAD)*500 - PAD;
      #pragma unroll
      for (int i=0;i<PASSES;i++){
        int c = i*256 + tid;
        if ((TOT % 256 == 0) || c < TOT){
          int e = c / CIG; int ci8 = (c % CIG)*8;
          int q = q0 + e;
          uint4 v = make_uint4(0u,0u,0u,0u);
          bool ok = ((unsigned)q < (unsigned)MAPN) && (!HASBN || ci8 < CIREAL);
          if (ok){
            v = *(const uint4*)(in + (size_t)q*CI + ci8);
            if (HASBN){
              ushort_t* hv = (ushort_t*)&v;
              #pragma unroll
              for (int j=0;j<8;j++){
                float f = bf2f(hv[j]);
                f = fmaxf(fmaf(f, sSc[ci8+j], sSh[ci8+j]), 0.0f);
                hv[j] = f2bf(f);
              }
            }
          }
          unsigned wa = ((unsigned)((e*CI + ci8)*2)) ^ ((unsigned)(e&7)<<4);
          *(uint4*)(sA + wa) = v;
        }
      }
    }
    __syncthreads();   // A writes + pending B prefetch drained

    for (int kw=0; kw<KS; kw++){
      int t = kh*KS + kw;
      // prefetch next tap's B (overlaps with this tap's compute)
      if (t+1 < NT){
        for (int s=wv; s<NSL; s+=4)
          glds16((const char*)wt + (size_t)(t+1)*TB + (size_t)s*1024 + lane*16,
                 &sB[cur^1][s*1024]);
      }
      bool aok[MI];
      #pragma unroll
      for (int mi=0;mi<MI;mi++){
        int xs = xc[mi] + kw - PAD;
        aok[mi] = pv[mi] && ((unsigned)xs < 500u);
      }
      #pragma unroll
      for (int kc=0;kc<KC;kc++){
        short8 bfr[NFW];
        #pragma unroll
        for (int ni=0;ni<NFW;ni++)
          bfr[ni] = *(const short8*)(&sB[cur][((kc*NF + wn*NFW + ni)<<10) + lane*16]);
        #pragma unroll
        for (int mi=0;mi<MI;mi++){
          int e = wm*(MI*16) + mi*16 + (lane&15) + kw;
          unsigned ra = ((unsigned)((e*CI + kc*32 + (lane>>4)*8)*2)) ^ ((unsigned)(e&7)<<4);
          short8 af = *(const short8*)(sA + ra);
          if (!aok[mi]) af = zfrag;
          #pragma unroll
          for (int ni=0;ni<NFW;ni++)
            acc[mi][ni] = __builtin_amdgcn_mfma_f32_16x16x32_bf16(af, bfr[ni], acc[mi][ni], 0,0,0);
        }
      }
      __syncthreads();
      cur ^= 1;
    }
  }

  // ---- epilogue: bf16 store + fused BN partial stats ----
  #pragma unroll
  for (int ni=0;ni<NFW;ni++){
    float ps=0.f, pq=0.f;
    #pragma unroll
    for (int mi=0;mi<MI;mi++){
      int prow = p0 + wm*(MI*16) + mi*16 + (lane>>4)*4;
      #pragma unroll
      for (int j=0;j<4;j++){
        float v = acc[mi][ni][j];
        int p = prow + j;
        if (p < MAPN){
          ps += v; pq += v*v;
          out[(size_t)p*COPAD + wn*(NFW*16) + ni*16 + (lane&15)] = f2bf(v);
        }
      }
    }
    ps += __shfl_xor(ps, 16); pq += __shfl_xor(pq, 16);
    ps += __shfl_xor(ps, 32); pq += __shfl_xor(pq, 32);
    if (lane < 16){ sStat[wv][ni][lane][0]=ps; sStat[wv][ni][lane][1]=pq; }
  }
  __syncthreads();
  if (tid < CO){
    int wn_ = tid / (NFW*16);
    int r = tid % (NFW*16);
    int ni_ = r >> 4, col = r & 15;
    float s = 0.f, q = 0.f;
    #pragma unroll
    for (int m=0;m<WM;m++){
      s += sStat[m*WN + wn_][ni_][col][0];
      q += sStat[m*WN + wn_][ni_][col][1];
    }
    partials[(size_t)blockIdx.x*(2*CO) + tid]      = s;
    partials[(size_t)blockIdx.x*(2*CO) + CO + tid] = q;
  }
}

// ---------------- BN: reduce per-block partials -> scale/shift ----------------
template<int CO>
__global__ void bn_reduce(const float* __restrict__ partials, int nblk,
                          const float* __restrict__ g, const float* __restrict__ b,
                          float* __restrict__ scsh){
  int c = blockIdx.x;
  float s=0.f, q=0.f;
  for (int i=threadIdx.x; i<nblk; i+=256){
    s += partials[(size_t)i*(2*CO) + c];
    q += partials[(size_t)i*(2*CO) + CO + c];
  }
  __shared__ float rs[256], rq[256];
  rs[threadIdx.x]=s; rq[threadIdx.x]=q; __syncthreads();
  for (int o=128;o;o>>=1){
    if (threadIdx.x<o){ rs[threadIdx.x]+=rs[threadIdx.x+o]; rq[threadIdx.x]+=rq[threadIdx.x+o]; }
    __syncthreads();
  }
  if (threadIdx.x==0){
    float mean = rs[0]*(1.0f/(float)MAPN);
    float var  = rq[0]*(1.0f/(float)MAPN) - mean*mean;
    float inv  = rsqrtf(var + 1e-5f);
    float sc   = g[c]*inv;
    scsh[c]    = sc;
    scsh[CO+c] = b[c] - mean*sc;
  }
}

// ---------------- final 1x1 conv + bias (fused input BN+ReLU), NCHW out ----------------
__global__ void conv5_kernel(const ushort_t* __restrict__ in, const float* __restrict__ w,
                             const float* __restrict__ bias, const float* __restrict__ scsh,
                             float* __restrict__ out){
  __shared__ float sw[21*48];
  __shared__ float sb[21];
  __shared__ float sc[48], sh[48];
  for (int i=threadIdx.x;i<1008;i+=256) sw[i]=w[i];
  if (threadIdx.x<21) sb[threadIdx.x]=bias[threadIdx.x];
  if (threadIdx.x<48){ sc[threadIdx.x]=scsh[threadIdx.x]; sh[threadIdx.x]=scsh[48+threadIdx.x]; }
  __syncthreads();
  int pix = blockIdx.x*256 + threadIdx.x;
  if (pix >= MAPN) return;
  float acc[21];
  #pragma unroll
  for (int i=0;i<21;i++) acc[i]=0.0f;
  const ushort_t* ip = in + (size_t)pix*64;
  #pragma unroll
  for (int cg=0; cg<6; cg++){
    uint4 v = *(const uint4*)(ip + cg*8);
    ushort_t* hv = (ushort_t*)&v;
    #pragma unroll
    for (int j=0;j<8;j++){
      int ci = cg*8+j;
      float s = fmaxf(fmaf(bf2f(hv[j]), sc[ci], sh[ci]), 0.0f);
      #pragma unroll
      for (int co=0;co<21;co++) acc[co]=fmaf(s, sw[co*48+ci], acc[co]);
    }
  }
  #pragma unroll
  for (int co=0;co<21;co++) out[(size_t)co*MAPN + pix] = acc[co] + sb[co];
}

// ---------------- host launch ----------------
static inline size_t al256(size_t x){ return (x + 255) & ~(size_t)255; }

extern "C" void kernel_launch(void* const* d_in, const int* in_sizes, int n_in,
                              void* d_out, int out_size, void* d_ws, size_t ws_size,
                              hipStream_t stream){
  const float* features = (const float*)d_in[0];
  const void*  proj     = d_in[1];
  const void*  mask     = d_in[2];
  const float* rgb      = (const float*)d_in[3];
  const float* w1 = (const float*)d_in[4];
  const float* g1 = (const float*)d_in[5];
  const float* b1 = (const float*)d_in[6];
  const float* w2 = (const float*)d_in[7];
  const float* g2 = (const float*)d_in[8];
  const float* b2 = (const float*)d_in[9];
  const float* w3 = (const float*)d_in[10];
  const float* g3 = (const float*)d_in[11];
  const float* b3 = (const float*)d_in[12];
  const float* w4 = (const float*)d_in[13];
  const float* g4 = (const float*)d_in[14];
  const float* b4 = (const float*)d_in[15];
  const float* w5 = (const float*)d_in[16];
  const float* b5 = (const float*)d_in[17];

  const int NBLK = (MAPN + 127)/128;   // 1954

  char* ws = (char*)d_ws;
  size_t off = 0;
  ushort_t* mem_bf = (ushort_t*)(ws + off); off += al256((size_t)MAPN*64*2);
  ushort_t* actA   = (ushort_t*)(ws + off); off += al256((size_t)MAPN*128*2);
  ushort_t* actB   = (ushort_t*)(ws + off); off += al256((size_t)MAPN*64*2);
  ushort_t* Fhwc   = (ushort_t*)(ws + off); off += al256((size_t)131072*64*2);
  int*      table  = (int*)(ws + off);      off += al256((size_t)NPIX*4);
  ushort_t* wh1    = (ushort_t*)(ws + off); off += al256((size_t)128*49*64*2);
  ushort_t* wh2    = (ushort_t*)(ws + off); off += al256((size_t)64*9*128*2);
  ushort_t* wh3    = (ushort_t*)(ws + off); off += al256((size_t)48*9*64*2);
  ushort_t* wh4    = (ushort_t*)(ws + off); off += al256((size_t)48*9*64*2);
  float*    partials = (float*)(ws + off);  off += al256((size_t)NBLK*2*128*4);
  int* blkSums = (int*)(ws + off); off += al256(2048*4);
  int* blkOffs = (int*)(ws + off); off += al256(2049*4);
  int* maxidx  = (int*)(ws + off); off += 256;
  int* flags   = (int*)(ws + off); off += 256;
  float* scsh1 = (float*)(ws + off); off += al256(256*4);
  float* scsh2 = (float*)(ws + off); off += al256(256*4);
  float* scsh3 = (float*)(ws + off); off += al256(256*4);
  float* scsh4 = (float*)(ws + off); off += al256(256*4);

  float* out_sem = (float*)d_out;
  float* out_obs = out_sem + (size_t)21*MAPN;
  float* out_rgb = out_obs + MAPN;

  detect_kernel<<<1,256,0,stream>>>((const int*)mask, (const int*)proj, flags);
  feat_transpose<<<dim3(8,256),256,0,stream>>>(features, Fhwc);

  scan_count<<<2048,256,0,stream>>>(mask, flags, blkSums);
  scan_offsets<<<1,256,0,stream>>>(blkSums, blkOffs);
  build_table<<<2048,256,0,stream>>>(mask, flags, blkOffs, table);

  hipMemsetAsync(maxidx, 0, 4, stream);
  max_idx_kernel<<<256,256,0,stream>>>(proj, flags, maxidx);

  // fragment-major weight packs
  wprep_frag<<<512,256,0,stream>>>(w1, wh1, 128, 64, 49, 2, 8);
  wprep_frag<<<128,256,0,stream>>>(w2, wh2, 64, 128, 9, 4, 4);
  wprep_frag<<<64,256,0,stream>>>(w3, wh3, 48, 64, 9, 2, 3);
  wprep_frag<<<64,256,0,stream>>>(w4, wh4, 48, 48, 9, 2, 3);

  gather_kernel<<<62500,256,0,stream>>>(proj, flags, maxidx, table, Fhwc, rgb,
                                        mem_bf, out_obs, out_rgb);

  // L1: 7x7 64->128, BN stats fused
  conv_khs<64,128,128,7,3,false,64,2,2><<<NBLK,256,0,stream>>>(mem_bf, wh1, nullptr, actA, partials);
  bn_reduce<128><<<128,256,0,stream>>>(partials, NBLK, g1, b1, scsh1);

  // L2: 3x3 128->64, input-BN(L1) fused into staging
  conv_khs<128,64,64,3,1,true,128,2,2><<<NBLK,256,0,stream>>>(actA, wh2, scsh1, actB, partials);
  bn_reduce<64><<<64,256,0,stream>>>(partials, NBLK, g2, b2, scsh2);

  // L3: 3x3 64->48 (pad 64), input-BN(L2) fused
  conv_khs<64,48,64,3,1,true,64,4,1><<<NBLK,256,0,stream>>>(actB, wh3, scsh2, actA, partials);
  bn_reduce<48><<<48,256,0,stream>>>(partials, NBLK, g3, b3, scsh3);

  // L4: 3x3 48(pad64)->48 (pad 64), input-BN(L3) fused (ci>=48 zeroed)
  conv_khs<64,48,64,3,1,true,48,4,1><<<NBLK,256,0,stream>>>(actA, wh4, scsh3, actB, partials);
  bn_reduce<48><<<48,256,0,stream>>>(partials, NBLK, g4, b4, scsh4);

  // L5: 1x1 48->21 + bias, input-BN(L4) fused, NCHW out
  conv5_kernel<<<(MAPN+255)/256,256,0,stream>>>(actB, w5, b5, scsh4, out_sem);
}